// Round 6
// baseline (457.436 us; speedup 1.0000x reference)
//
#include <hip/hip_runtime.h>
#include <hip/hip_cooperative_groups.h>

namespace cg = cooperative_groups;

#define BATCH 16384
#define N1 (BATCH * 196)
#define N2 (BATCH * 49)
#define VBLK 1024   // virtual blocks for P1/P2
#define SPB  16     // samples per virtual block

// ws layout (bytes):
//   [0, 8192)             : double stats, 2 layers x 64 slots x 64B line (sum,sumsq)
//   [8192, 57472)         : wstream: 4 partitions x 307 records x 10 floats
//   [57472, 59432)        : wfc1s : w_fc1^T contiguous [49][10]
//   [59440, 71984)        : wk1   : per-pos fused L1 weights [196][16]
//   [71984, 75120)        : wk2   : per-pos fused L2 weights [49][16]
//   [75136, 12920192)     : l1buf BATCH*196 floats
//   [12920192, 16328064)  : l2buf BATCH*52 floats (stride-52 padded)
#define WS_WSTREAM_OFF 8192
#define WS_WFC1S_OFF   57472
#define WS_WK1_OFF     59440
#define WS_WK2_OFF     71984
#define WS_L1_OFF      75136
#define WS_L2_OFF      12920192

// ---------- compile-time pair index <-> (p,q) ----------
__host__ __device__ constexpr int pair_p(int i) {
    int p = 0, rem = i;
    while (rem >= 49 - p) { rem -= 49 - p; ++p; }
    return p;
}
__host__ __device__ constexpr int pair_q(int i) {
    int p = 0, rem = i;
    while (rem >= 49 - p) { rem -= 49 - p; ++p; }
    return p + rem;
}

struct Args {
    const float *x, *l1w1, *wA, *wB, *wC, *wD, *l1w3, *l2w1, *l2w2, *l2w4;
    const float *wfc1, *bfc1, *wf2, *bfc2, *gamma, *beta;
    float *wstream, *wfc1s, *wk1, *wk2, *l1buf, *l2buf;
    double *stats;
    float *out;
};

__device__ __forceinline__ void block_stats2(float s, float ss, double* slotp,
                                             float* wls, float* wlss) {
    #pragma unroll
    for (int off = 32; off; off >>= 1) {
        s  += __shfl_down(s, off);
        ss += __shfl_down(ss, off);
    }
    int lane = threadIdx.x & 63, wid = threadIdx.x >> 6;
    if (lane == 0) { wls[wid] = s; wlss[wid] = ss; }
    __syncthreads();
    if (threadIdx.x == 0) {
        atomicAdd(&slotp[0], (double)(wls[0] + wls[1] + wls[2] + wls[3]));
        atomicAdd(&slotp[1], (double)(wlss[0] + wlss[1] + wlss[2] + wlss[3]));
    }
}

// first wave: reduce 64 slots -> (a, c) into bcast[0..1]
__device__ __forceinline__ void stats_reduce(const double* __restrict__ layer,
                                             const float* __restrict__ gamma,
                                             const float* __restrict__ beta,
                                             double inv_n, float* bcast) {
    int t = threadIdx.x;
    if (t < 64) {
        double s  = layer[t * 8];
        double ss = layer[t * 8 + 1];
        #pragma unroll
        for (int off = 32; off; off >>= 1) {
            s  += __shfl_xor(s, off);
            ss += __shfl_xor(ss, off);
        }
        if (t == 0) {
            double mean = s * inv_n;
            double var  = ss * inv_n - mean * mean;
            float a = (float)((double)gamma[0] / sqrt(var + 1e-5));
            bcast[0] = a;
            bcast[1] = beta[0] - (float)mean * a;
        }
    }
}

// ---------- FC2 pair stream, 4-way partition, compile-time (p,q) ----------
template<int W, int J>
__device__ __forceinline__ void fc2_steps(const float* __restrict__ wb,
                                          const float* v, float* acc) {
    constexpr int i = J * 4 + W;
    if constexpr (i < 1225) {
        constexpr int p = pair_p(i);
        constexpr int q = pair_q(i);
        float pv = v[p] * v[q];
        const float* w = wb + J * 10;
        #pragma unroll
        for (int o = 0; o < 10; ++o) acc[o] = fmaf(pv, w[o], acc[o]);
        fc2_steps<W, J + 1>(wb, v, acc);
    }
}

template<int W>
__device__ __forceinline__ void fc_all(const float* __restrict__ wstream,
                                       const float* __restrict__ wfc1s,
                                       const float* v, float* acc) {
    #pragma unroll
    for (int k = 0; k < 49; ++k) {
        if ((k & 3) == W) {
            const float* w = wfc1s + k * 10;
            #pragma unroll
            for (int o = 0; o < 10; ++o) acc[o] = fmaf(v[k], w[o], acc[o]);
        }
    }
    fc2_steps<W, 0>(wstream + W * 3070, v, acc);
}

__global__ void __launch_bounds__(256, 4) fused(Args a) {
    __shared__ __align__(16) float smem[6272];   // 25088 B, reused per phase
    __shared__ float wls[4], wlss[4];
    __shared__ float bcast[2];
    cg::grid_group grid = cg::this_grid();
    int t = threadIdx.x;
    int G = gridDim.x;

    // ================= P0: zero stats + weight prep =================
    {
        if (blockIdx.x == 0) {
            for (int z = t; z < 1024; z += 256) a.stats[z] = 0.0;
        }
        int i = blockIdx.x * 256 + t;
        if (i < 1225) {
            int rem = i, p = 0;
            while (rem >= 49 - p) { rem -= 49 - p; ++p; }
            int q = p + rem;
            int col = p * 49 + q;
            int slot = ((i & 3) * 307 + (i >> 2)) * 10;
            #pragma unroll
            for (int o = 0; o < 10; ++o) a.wstream[slot + o] = a.wf2[o * 2401 + col];
        }
        if (i < 196) {
            int pi = i / 14, pj = i - 14 * pi;
            int r0 = 2 * pi * 28 + 2 * pj;
            float* o = a.wk1 + i * 16;
            o[0] = a.l1w1[r0];      o[1] = a.l1w1[r0 + 1];
            o[2] = a.l1w1[r0 + 28]; o[3] = a.l1w1[r0 + 29];
            float mA[4] = { pj != 0 ? 1.f : 0.f, pj != 13 ? 1.f : 0.f,
                            pj != 0 ? 1.f : 0.f, pj != 13 ? 1.f : 0.f };
            float mB[4] = { pi != 0 ? 1.f : 0.f, pi != 0 ? 1.f : 0.f,
                            pi != 13 ? 1.f : 0.f, pi != 13 ? 1.f : 0.f };
            const int e1[10] = {0,1,2,3,0,0,0,1,1,2};
            const int e2[10] = {0,1,2,3,1,2,3,2,3,3};
            int wo = pi * 140 + 10 * pj;
            #pragma unroll
            for (int k = 0; k < 10; ++k) {
                float cA = mA[e1[k]] * mA[e2[k]];
                float cB = mB[e1[k]] * mB[e2[k]];
                o[4 + k] = a.wA[wo + k] * cA + a.wB[wo + k] * cB
                         + a.wC[wo + k] * cA * cB + a.wD[wo + k];
            }
            o[14] = a.l1w3[i];
            o[15] = 0.f;
        }
        if (i < 49) {
            int pi = i / 7, pj = i - 7 * pi;
            int r0 = 2 * pi * 14 + 2 * pj;
            float* o = a.wk2 + i * 16;
            o[0] = a.l2w1[r0];      o[1] = a.l2w1[r0 + 1];
            o[2] = a.l2w1[r0 + 14]; o[3] = a.l2w1[r0 + 15];
            #pragma unroll
            for (int k = 0; k < 10; ++k) o[4 + k] = a.l2w2[pi * 70 + 10 * pj + k];
            o[14] = a.l2w4[i];
            o[15] = 0.f;
            #pragma unroll
            for (int o2 = 0; o2 < 10; ++o2) a.wfc1s[i * 10 + o2] = a.wfc1[o2 * 49 + i];
        }
    }
    __threadfence();
    grid.sync();

    // ================= P1: layer 1 =================
    {
        bool active = t < 196;
        int pos = active ? t : 0;
        int pi = pos / 14, pj = pos - 14 * pi;
        const float4* wp = (const float4*)(a.wk1 + pos * 16);
        float4 w0 = wp[0], w1 = wp[1], w2 = wp[2], w3 = wp[3];
        int r0 = (2 * pi) * 28 + 2 * pj;
        float sum = 0.f, sumsq = 0.f;
        for (int vb = blockIdx.x; vb < VBLK; vb += G) {
            for (int tile = 0; tile < 2; ++tile) {
                __syncthreads();   // previous compute done before overwrite
                const float4* src = (const float4*)(a.x + ((size_t)vb * SPB + tile * 8) * 784);
                float4* dst = (float4*)smem;
                #pragma unroll
                for (int i2 = 0; i2 < 6; ++i2) dst[t + 256 * i2] = src[t + 256 * i2];
                if (t < 32) dst[t + 1536] = src[t + 1536];
                __syncthreads();
                int sbase = vb * SPB + tile * 8;
                #pragma unroll
                for (int s = 0; s < 8; ++s) {
                    const float* xb = smem + s * 784;
                    float2 tp = *(const float2*)(xb + r0);
                    float2 bo = *(const float2*)(xb + r0 + 28);
                    float b00 = tp.x, b01 = tp.y, b10 = bo.x, b11 = bo.y;
                    float acc = b00 * w0.x + b01 * w0.y + b10 * w0.z + b11 * w0.w;
                    acc += b00 * b00 * w1.x + b01 * b01 * w1.y + b10 * b10 * w1.z + b11 * b11 * w1.w;
                    acc += b00 * b01 * w2.x + b00 * b10 * w2.y + b00 * b11 * w2.z + b01 * b10 * w2.w;
                    acc += b01 * b11 * w3.x + b10 * b11 * w3.y + w3.z;
                    if (active) {
                        a.l1buf[(size_t)(sbase + s) * 196 + pos] = acc;
                        sum += acc;
                        sumsq += acc * acc;
                    }
                }
            }
        }
        block_stats2(sum, sumsq, a.stats + (blockIdx.x & 63) * 8, wls, wlss);
    }
    __threadfence();
    grid.sync();

    // ================= P2: layer 2 =================
    {
        stats_reduce(a.stats, a.gamma, a.beta, 1.0 / (double)N1, bcast);
        bool active = t < 196;
        int tt = active ? t : 0;
        int sub = tt / 49;
        int pos = tt - 49 * sub;
        int pi = pos / 7, pj = pos - 7 * pi;
        const float4* wp = (const float4*)(a.wk2 + pos * 16);
        float4 w0 = wp[0], q1 = wp[1], q2 = wp[2], q3 = wp[3];
        int r0 = (2 * pi) * 14 + 2 * pj;
        float sum = 0.f, sumsq = 0.f;
        for (int vb = blockIdx.x; vb < VBLK; vb += G) {
            for (int tile = 0; tile < 2; ++tile) {
                __syncthreads();
                const float4* src = (const float4*)(a.l1buf + ((size_t)vb * SPB + tile * 8) * 196);
                float4* dst = (float4*)smem;
                dst[t] = src[t];
                if (t < 136) dst[t + 256] = src[t + 256];
                __syncthreads();
                float a1 = bcast[0], c1 = bcast[1];
                int sbase = vb * SPB + tile * 8;
                #pragma unroll
                for (int s2 = 0; s2 < 2; ++s2) {
                    int sl = s2 * 4 + sub;
                    const float* hb = smem + sl * 196;
                    float2 tp = *(const float2*)(hb + r0);
                    float2 bo = *(const float2*)(hb + r0 + 14);
                    float h00 = fmaf(a1, tp.x, c1), h01 = fmaf(a1, tp.y, c1);
                    float h10 = fmaf(a1, bo.x, c1), h11 = fmaf(a1, bo.y, c1);
                    float acc = h00 * w0.x + h01 * w0.y + h10 * w0.z + h11 * w0.w;
                    acc += h00 * h00 * q1.x + h01 * h01 * q1.y + h10 * h10 * q1.z + h11 * h11 * q1.w;
                    acc += h00 * h01 * q2.x + h00 * h10 * q2.y + h00 * h11 * q2.z + h01 * h10 * q2.w;
                    acc += h01 * h11 * q3.x + h10 * h11 * q3.y + q3.z;
                    if (active) {
                        a.l2buf[(size_t)(sbase + sl) * 52 + pos] = acc;
                        sum += acc;
                        sumsq += acc * acc;
                    }
                }
            }
        }
        block_stats2(sum, sumsq, a.stats + 512 + (blockIdx.x & 63) * 8, wls, wlss);
    }
    __threadfence();
    grid.sync();

    // ================= P3: FC =================
    {
        stats_reduce(a.stats + 512, a.gamma, a.beta, 1.0 / (double)N2, bcast);
        int lane = t & 63;
        int wid  = t >> 6;
        float (*part)[64][10] = (float (*)[64][10])smem;   // 4*64*10 floats
        for (int vb = blockIdx.x; vb < 256; vb += G) {
            float v[52];
            const float4* src = (const float4*)(a.l2buf + ((size_t)vb * 64 + lane) * 52);
            #pragma unroll
            for (int k = 0; k < 13; ++k) *(float4*)(v + 4 * k) = src[k];
            __syncthreads();   // bcast ready; previous iter's part reads done
            float a2 = bcast[0], c2 = bcast[1];
            #pragma unroll
            for (int k = 0; k < 49; ++k) v[k] = fmaf(a2, v[k], c2);

            float acc[10];
            #pragma unroll
            for (int o = 0; o < 10; ++o) acc[o] = 0.f;

            int wu = __builtin_amdgcn_readfirstlane(wid);
            switch (wu) {
                case 0:  fc_all<0>(a.wstream, a.wfc1s, v, acc); break;
                case 1:  fc_all<1>(a.wstream, a.wfc1s, v, acc); break;
                case 2:  fc_all<2>(a.wstream, a.wfc1s, v, acc); break;
                default: fc_all<3>(a.wstream, a.wfc1s, v, acc); break;
            }

            #pragma unroll
            for (int o = 0; o < 10; ++o) part[wid][lane][o] = acc[o];
            __syncthreads();

            for (int idx = t; idx < 640; idx += 256) {
                int sl = idx / 10, o = idx - 10 * sl;
                float r = part[0][sl][o] + part[1][sl][o] + part[2][sl][o] + part[3][sl][o];
                a.out[(size_t)(vb * 64 + sl) * 10 + o] = r + a.bfc1[o] + a.bfc2[o];
            }
        }
    }
}

extern "C" void kernel_launch(void* const* d_in, const int* in_sizes, int n_in,
                              void* d_out, int out_size, void* d_ws, size_t ws_size,
                              hipStream_t stream) {
    char* ws = (char*)d_ws;
    Args a;
    a.x     = (const float*)d_in[0];
    a.l1w1  = (const float*)d_in[1];
    a.wA    = (const float*)d_in[2];
    a.wB    = (const float*)d_in[3];
    a.wC    = (const float*)d_in[4];
    a.wD    = (const float*)d_in[5];
    a.l1w3  = (const float*)d_in[6];
    a.l2w1  = (const float*)d_in[7];
    a.l2w2  = (const float*)d_in[8];
    a.l2w4  = (const float*)d_in[9];
    a.wfc1  = (const float*)d_in[10];
    a.bfc1  = (const float*)d_in[11];
    a.wf2   = (const float*)d_in[12];
    a.bfc2  = (const float*)d_in[13];
    a.gamma = (const float*)d_in[14];
    a.beta  = (const float*)d_in[15];
    a.wstream = (float*)(ws + WS_WSTREAM_OFF);
    a.wfc1s   = (float*)(ws + WS_WFC1S_OFF);
    a.wk1     = (float*)(ws + WS_WK1_OFF);
    a.wk2     = (float*)(ws + WS_WK2_OFF);
    a.l1buf   = (float*)(ws + WS_L1_OFF);
    a.l2buf   = (float*)(ws + WS_L2_OFF);
    a.stats   = (double*)ws;
    a.out     = (float*)d_out;

    int nb = 0;
    hipOccupancyMaxActiveBlocksPerMultiprocessor(&nb, (const void*)fused, 256, 0);
    int dev = 0, cus = 0;
    hipGetDevice(&dev);
    hipDeviceGetAttribute(&cus, hipDeviceAttributeMultiprocessorCount, dev);
    int grid = nb * cus;
    if (grid > VBLK) grid = VBLK;
    if (grid < 1) grid = 1;

    void* args[] = { &a };
    hipLaunchCooperativeKernel((const void*)fused, dim3(grid), dim3(256), args, 0, stream);
}

// Round 7
// 57.101 us; speedup vs baseline: 8.0110x; 8.0110x over previous
//
#include <hip/hip_runtime.h>

#define BATCH 16384
#define N1 (BATCH * 196)
#define N2 (BATCH * 49)

// ws layout (bytes):
//   [0, 8192)             : double stats, 2 layers x 64 slots x 64B line (sum,sumsq)
//   [8192, 57472)         : wstream: 16 partitions x 77 records x 10 floats (49280B)
//   [57472, 59432)        : wfc1s : w_fc1^T contiguous [49][10]
//   [59440, 71984)        : wk1   : per-pos fused L1 weights [196][16]
//   [71984, 75120)        : wk2   : per-pos fused L2 weights [49][16]
//   [75136, 12920192)     : l1buf BATCH*196 floats
//   [12920192, 16328064)  : l2buf BATCH*52 floats (stride-52 padded)
#define WS_WSTREAM_OFF 8192
#define WS_WFC1S_OFF   57472
#define WS_WK1_OFF     59440
#define WS_WK2_OFF     71984
#define WS_L1_OFF      75136
#define WS_L2_OFF      12920192

#define S1 8      // samples per k1 block
#define S2TOT 8   // samples per k2 block
#define NPART 16  // k3 pair partitions (waves per block)

// ---------- compile-time pair index <-> (p,q) ----------
__host__ __device__ constexpr int pair_p(int i) {
    int p = 0, rem = i;
    while (rem >= 49 - p) { rem -= 49 - p; ++p; }
    return p;
}
__host__ __device__ constexpr int pair_q(int i) {
    int p = 0, rem = i;
    while (rem >= 49 - p) { rem -= 49 - p; ++p; }
    return p + rem;
}

// block reduce -> one atomicAdd pair into this block's slot (64 slots, 64B apart)
__device__ __forceinline__ void block_stats2(float s, float ss, double* slotp,
                                             float* wls, float* wlss) {
    #pragma unroll
    for (int off = 32; off; off >>= 1) {
        s  += __shfl_down(s, off);
        ss += __shfl_down(ss, off);
    }
    int lane = threadIdx.x & 63, wid = threadIdx.x >> 6;
    if (lane == 0) { wls[wid] = s; wlss[wid] = ss; }
    __syncthreads();
    if (threadIdx.x == 0) {
        atomicAdd(&slotp[0], (double)(wls[0] + wls[1] + wls[2] + wls[3]));
        atomicAdd(&slotp[1], (double)(wlss[0] + wlss[1] + wlss[2] + wlss[3]));
    }
}

// first wave: reduce 64 slots -> (a, c) into bcast[0..1]
__device__ __forceinline__ void stats_reduce(const double* __restrict__ layer,
                                             const float* __restrict__ gamma,
                                             const float* __restrict__ beta,
                                             double inv_n, float* bcast) {
    int t = threadIdx.x;
    if (t < 64) {
        double s  = layer[t * 8];
        double ss = layer[t * 8 + 1];
        #pragma unroll
        for (int off = 32; off; off >>= 1) {
            s  += __shfl_xor(s, off);
            ss += __shfl_xor(ss, off);
        }
        if (t == 0) {
            double mean = s * inv_n;
            double var  = ss * inv_n - mean * mean;
            float a = (float)((double)gamma[0] / sqrt(var + 1e-5));
            bcast[0] = a;
            bcast[1] = beta[0] - (float)mean * a;
        }
    }
}

// ---------- prep: zero stats, fuse masks into weights, reorder w_fc2 ----------
__global__ void __launch_bounds__(256) kprep(
        const float* __restrict__ wf2, const float* __restrict__ wfc1,
        const float* __restrict__ l1w1, const float* __restrict__ wA,
        const float* __restrict__ wB, const float* __restrict__ wC,
        const float* __restrict__ wD, const float* __restrict__ l1w3,
        const float* __restrict__ l2w1, const float* __restrict__ l2w2,
        const float* __restrict__ l2w4,
        double* __restrict__ stats,
        float* __restrict__ wstream, float* __restrict__ wfc1s,
        float* __restrict__ wk1, float* __restrict__ wk2) {
    int i = blockIdx.x * 256 + threadIdx.x;
    if (blockIdx.x == 0) {
        #pragma unroll
        for (int z = 0; z < 4; ++z) stats[threadIdx.x + 256 * z] = 0.0;
    }
    if (i < 1225) {
        int rem = i, p = 0;
        while (rem >= 49 - p) { rem -= 49 - p; ++p; }
        int q = p + rem;
        int col = p * 49 + q;
        int slot = ((i & (NPART - 1)) * 77 + (i / NPART)) * 10;
        #pragma unroll
        for (int o = 0; o < 10; ++o) wstream[slot + o] = wf2[o * 2401 + col];
    }
    if (i < 196) {
        int pi = i / 14, pj = i - 14 * pi;
        int r0 = 2 * pi * 28 + 2 * pj;
        float* o = wk1 + i * 16;
        o[0] = l1w1[r0];      o[1] = l1w1[r0 + 1];
        o[2] = l1w1[r0 + 28]; o[3] = l1w1[r0 + 29];
        float mA[4] = { pj != 0 ? 1.f : 0.f, pj != 13 ? 1.f : 0.f,
                        pj != 0 ? 1.f : 0.f, pj != 13 ? 1.f : 0.f };
        float mB[4] = { pi != 0 ? 1.f : 0.f, pi != 0 ? 1.f : 0.f,
                        pi != 13 ? 1.f : 0.f, pi != 13 ? 1.f : 0.f };
        const int e1[10] = {0,1,2,3,0,0,0,1,1,2};
        const int e2[10] = {0,1,2,3,1,2,3,2,3,3};
        int wo = pi * 140 + 10 * pj;
        #pragma unroll
        for (int t = 0; t < 10; ++t) {
            float cA = mA[e1[t]] * mA[e2[t]];
            float cB = mB[e1[t]] * mB[e2[t]];
            o[4 + t] = wA[wo + t] * cA + wB[wo + t] * cB
                     + wC[wo + t] * cA * cB + wD[wo + t];
        }
        o[14] = l1w3[i];
        o[15] = 0.f;
    }
    if (i < 49) {
        int pi = i / 7, pj = i - 7 * pi;
        int r0 = 2 * pi * 14 + 2 * pj;
        float* o = wk2 + i * 16;
        o[0] = l2w1[r0];      o[1] = l2w1[r0 + 1];
        o[2] = l2w1[r0 + 14]; o[3] = l2w1[r0 + 15];
        #pragma unroll
        for (int t = 0; t < 10; ++t) o[4 + t] = l2w2[pi * 70 + 10 * pj + t];
        o[14] = l2w4[i];
        o[15] = 0.f;
        #pragma unroll
        for (int o2 = 0; o2 < 10; ++o2) wfc1s[i * 10 + o2] = wfc1[o2 * 49 + i];
    }
}

// ---------- layer 1: LDS-staged, coalesced float4 global loads ----------
__global__ void __launch_bounds__(256) k1(const float* __restrict__ x,
                                          const float* __restrict__ wk1,
                                          float* __restrict__ l1out,
                                          double* __restrict__ stats) {
    __shared__ float xs[S1 * 784];   // 25088 B
    __shared__ float wls[4], wlss[4];
    int t = threadIdx.x;
    const float4* src = (const float4*)(x + (size_t)blockIdx.x * (S1 * 784));
    float4* dst = (float4*)xs;
    #pragma unroll
    for (int i = 0; i < 6; ++i) dst[t + 256 * i] = src[t + 256 * i];
    if (t < 32) dst[t + 1536] = src[t + 1536];   // 1568 = 6*256 + 32

    bool active = t < 196;
    int pos = active ? t : 0;
    int pi = pos / 14, pj = pos - 14 * pi;
    const float4* wp = (const float4*)(wk1 + pos * 16);
    float4 a0 = wp[0], a1 = wp[1], a2 = wp[2], a3 = wp[3];
    int r0 = (2 * pi) * 28 + 2 * pj;
    int sbase = blockIdx.x * S1;
    __syncthreads();

    float sum = 0.f, sumsq = 0.f;
    #pragma unroll
    for (int s = 0; s < S1; ++s) {
        const float* xb = xs + s * 784;
        float2 tp = *(const float2*)(xb + r0);
        float2 bo = *(const float2*)(xb + r0 + 28);
        float b00 = tp.x, b01 = tp.y, b10 = bo.x, b11 = bo.y;
        float acc = b00 * a0.x + b01 * a0.y + b10 * a0.z + b11 * a0.w;
        acc += b00 * b00 * a1.x + b01 * b01 * a1.y + b10 * b10 * a1.z + b11 * b11 * a1.w;
        acc += b00 * b01 * a2.x + b00 * b10 * a2.y + b00 * b11 * a2.z + b01 * b10 * a2.w;
        acc += b01 * b11 * a3.x + b10 * b11 * a3.y + a3.z;
        if (active) {
            l1out[(size_t)(sbase + s) * 196 + pos] = acc;
            sum += acc;
            sumsq += acc * acc;
        }
    }
    block_stats2(sum, sumsq, stats + (blockIdx.x & 63) * 8, wls, wlss);
}

// ---------- layer 2: LDS-staged, writes stride-52 padded ----------
__global__ void __launch_bounds__(256) k2(const float* __restrict__ l1buf,
                                          const float* __restrict__ wk2,
                                          const float* __restrict__ gamma,
                                          const float* __restrict__ beta,
                                          double* __restrict__ stats,
                                          float* __restrict__ l2out) {
    __shared__ float hs[S2TOT * 196];  // 6272 B
    __shared__ float wls[4], wlss[4];
    __shared__ float bcast[2];
    int t = threadIdx.x;

    const float4* src = (const float4*)(l1buf + (size_t)blockIdx.x * (S2TOT * 196));
    float4* dst = (float4*)hs;
    dst[t] = src[t];
    if (t < 136) dst[t + 256] = src[t + 256];

    stats_reduce(stats, gamma, beta, 1.0 / (double)N1, bcast);

    bool active = t < 196;
    int tt = active ? t : 0;
    int sub = tt / 49;
    int pos = tt - 49 * sub;
    int pi = pos / 7, pj = pos - 7 * pi;
    const float4* wp = (const float4*)(wk2 + pos * 16);
    float4 a0 = wp[0], q1 = wp[1], q2 = wp[2], q3 = wp[3];
    int r0 = (2 * pi) * 14 + 2 * pj;
    int sbase = blockIdx.x * S2TOT;
    __syncthreads();
    float a1 = bcast[0], c1 = bcast[1];

    float sum = 0.f, sumsq = 0.f;
    #pragma unroll
    for (int s = 0; s < S2TOT / 4; ++s) {
        int sl = s * 4 + sub;
        const float* hb = hs + sl * 196;
        float2 tp = *(const float2*)(hb + r0);
        float2 bo = *(const float2*)(hb + r0 + 14);
        float h00 = fmaf(a1, tp.x, c1), h01 = fmaf(a1, tp.y, c1);
        float h10 = fmaf(a1, bo.x, c1), h11 = fmaf(a1, bo.y, c1);
        float acc = h00 * a0.x + h01 * a0.y + h10 * a0.z + h11 * a0.w;
        acc += h00 * h00 * q1.x + h01 * h01 * q1.y + h10 * h10 * q1.z + h11 * h11 * q1.w;
        acc += h00 * h01 * q2.x + h00 * h10 * q2.y + h00 * h11 * q2.z + h01 * h10 * q2.w;
        acc += h01 * h11 * q3.x + h10 * h11 * q3.y + q3.z;
        if (active) {
            l2out[(size_t)(sbase + sl) * 52 + pos] = acc;
            sum += acc;
            sumsq += acc * acc;
        }
    }
    block_stats2(sum, sumsq, stats + 512 + (blockIdx.x & 63) * 8, wls, wlss);
}

// ---------- FC: 16 pair-partitions (one per wave), compile-time (p,q) ----------
template<int W, int J>
__device__ __forceinline__ void fc2_steps(const float* __restrict__ wb,
                                          const float* v, float* acc) {
    constexpr int i = J * NPART + W;
    if constexpr (i < 1225) {
        constexpr int p = pair_p(i);
        constexpr int q = pair_q(i);
        float pv = v[p] * v[q];
        const float* w = wb + J * 10;
        #pragma unroll
        for (int o = 0; o < 10; ++o) acc[o] = fmaf(pv, w[o], acc[o]);
        fc2_steps<W, J + 1>(wb, v, acc);
    }
}

template<int W>
__device__ __forceinline__ void fc_all(const float* __restrict__ wstream,
                                       const float* __restrict__ wfc1s,
                                       const float* v, float* acc) {
    #pragma unroll
    for (int k = 0; k < 49; ++k) {
        if ((k & (NPART - 1)) == W) {
            const float* w = wfc1s + k * 10;
            #pragma unroll
            for (int o = 0; o < 10; ++o) acc[o] = fmaf(v[k], w[o], acc[o]);
        }
    }
    fc2_steps<W, 0>(wstream + W * 770, v, acc);
}

__global__ void __launch_bounds__(1024) k3(const float* __restrict__ l2buf,
                                           const float* __restrict__ wstream,
                                           const float* __restrict__ wfc1s,
                                           const float* __restrict__ b_fc1,
                                           const float* __restrict__ b_fc2,
                                           const float* __restrict__ gamma,
                                           const float* __restrict__ beta,
                                           const double* __restrict__ stats,
                                           float* __restrict__ out) {
    __shared__ float part[NPART][64][10];   // 40960 B
    __shared__ float bcast[2];
    int t = threadIdx.x;
    int lane = t & 63;
    int wid  = t >> 6;
    int s = blockIdx.x * 64 + lane;

    // issue v loads first (latency overlaps the stats reduce)
    float v[52];
    const float4* src = (const float4*)(l2buf + (size_t)s * 52);
    #pragma unroll
    for (int k = 0; k < 13; ++k) *(float4*)(v + 4 * k) = src[k];

    stats_reduce(stats + 512, gamma, beta, 1.0 / (double)N2, bcast);
    __syncthreads();
    float a2 = bcast[0], c2 = bcast[1];

    #pragma unroll
    for (int k = 0; k < 49; ++k) v[k] = fmaf(a2, v[k], c2);

    float acc[10];
    #pragma unroll
    for (int o = 0; o < 10; ++o) acc[o] = 0.f;

    int wu = __builtin_amdgcn_readfirstlane(wid);
    switch (wu) {
        case 0:  fc_all<0>(wstream, wfc1s, v, acc); break;
        case 1:  fc_all<1>(wstream, wfc1s, v, acc); break;
        case 2:  fc_all<2>(wstream, wfc1s, v, acc); break;
        case 3:  fc_all<3>(wstream, wfc1s, v, acc); break;
        case 4:  fc_all<4>(wstream, wfc1s, v, acc); break;
        case 5:  fc_all<5>(wstream, wfc1s, v, acc); break;
        case 6:  fc_all<6>(wstream, wfc1s, v, acc); break;
        case 7:  fc_all<7>(wstream, wfc1s, v, acc); break;
        case 8:  fc_all<8>(wstream, wfc1s, v, acc); break;
        case 9:  fc_all<9>(wstream, wfc1s, v, acc); break;
        case 10: fc_all<10>(wstream, wfc1s, v, acc); break;
        case 11: fc_all<11>(wstream, wfc1s, v, acc); break;
        case 12: fc_all<12>(wstream, wfc1s, v, acc); break;
        case 13: fc_all<13>(wstream, wfc1s, v, acc); break;
        case 14: fc_all<14>(wstream, wfc1s, v, acc); break;
        default: fc_all<15>(wstream, wfc1s, v, acc); break;
    }

    #pragma unroll
    for (int o = 0; o < 10; ++o) part[wid][lane][o] = acc[o];
    __syncthreads();

    if (t < 640) {
        int sl = t / 10, o = t - 10 * sl;
        float r = 0.f;
        #pragma unroll
        for (int w = 0; w < NPART; ++w) r += part[w][sl][o];
        out[(size_t)(blockIdx.x * 64 + sl) * 10 + o] = r + b_fc1[o] + b_fc2[o];
    }
}

extern "C" void kernel_launch(void* const* d_in, const int* in_sizes, int n_in,
                              void* d_out, int out_size, void* d_ws, size_t ws_size,
                              hipStream_t stream) {
    const float* x       = (const float*)d_in[0];
    const float* l1_w1   = (const float*)d_in[1];
    const float* l1_w2_1 = (const float*)d_in[2];
    const float* l1_w2_2 = (const float*)d_in[3];
    const float* l1_w2_3 = (const float*)d_in[4];
    const float* l1_w2_4 = (const float*)d_in[5];
    const float* l1_w3   = (const float*)d_in[6];
    const float* l2_w1   = (const float*)d_in[7];
    const float* l2_w2   = (const float*)d_in[8];
    const float* l2_w4   = (const float*)d_in[9];
    const float* w_fc1   = (const float*)d_in[10];
    const float* b_fc1   = (const float*)d_in[11];
    const float* w_fc2   = (const float*)d_in[12];
    const float* b_fc2   = (const float*)d_in[13];
    const float* bn_gamma = (const float*)d_in[14];
    const float* bn_beta  = (const float*)d_in[15];

    char* ws = (char*)d_ws;
    double* stats  = (double*)ws;
    float* wstream = (float*)(ws + WS_WSTREAM_OFF);
    float* wfc1s   = (float*)(ws + WS_WFC1S_OFF);
    float* wk1     = (float*)(ws + WS_WK1_OFF);
    float* wk2     = (float*)(ws + WS_WK2_OFF);
    float* l1buf   = (float*)(ws + WS_L1_OFF);
    float* l2buf   = (float*)(ws + WS_L2_OFF);
    float* out = (float*)d_out;

    kprep<<<5, 256, 0, stream>>>(w_fc2, w_fc1, l1_w1, l1_w2_1, l1_w2_2, l1_w2_3,
                                 l1_w2_4, l1_w3, l2_w1, l2_w2, l2_w4,
                                 stats, wstream, wfc1s, wk1, wk2);
    k1<<<BATCH / S1, 256, 0, stream>>>(x, wk1, l1buf, stats);
    k2<<<BATCH / S2TOT, 256, 0, stream>>>(l1buf, wk2, bn_gamma, bn_beta, stats, l2buf);
    k3<<<BATCH / 64, 1024, 0, stream>>>(l2buf, wstream, wfc1s, b_fc1, b_fc2,
                                        bn_gamma, bn_beta, stats, out);
}

// Round 8
// 48.340 us; speedup vs baseline: 9.4629x; 1.1812x over previous
//
#include <hip/hip_runtime.h>

#define BATCH 16384
#define N1 (BATCH * 196)
#define N2 (BATCH * 49)
#define S1 8   // samples per k1/k2 block

// ws layout (bytes):
//   [0, 32768)            : partials1, 2048 x (sum,sumsq) doubles
//   [32768, 65536)        : partials2, 2048 x (sum,sumsq) doubles
//   [65536, 165536)       : w2s: symmetric FC table [50][50][10] floats (100000 B)
//   [262144, 6684672)     : l1g: bf16 gathered layout BATCH*196 ushort
//   [6684672, 10092544)   : l2g: BATCH*52 floats (stride-52 padded)
#define WS_P1_OFF   0
#define WS_P2_OFF   32768
#define WS_W2S_OFF  65536
#define WS_L1G_OFF  262144
#define WS_L2G_OFF  6684672

__device__ __forceinline__ unsigned short f2bf(float f) {
    unsigned u = __float_as_uint(f);
    unsigned r = (u + 0x7FFFu + ((u >> 16) & 1u)) >> 16;   // RTNE
    return (unsigned short)r;
}
__device__ __forceinline__ float bf2f(unsigned short h) {
    return __uint_as_float((unsigned)h << 16);
}

// ---------------- k1: layer 1 (self-prep weights, bf16 gathered out, partial stats) ----------------
__global__ void __launch_bounds__(256) k1(
        const float* __restrict__ x,
        const float* __restrict__ l1w1, const float* __restrict__ wA,
        const float* __restrict__ wB, const float* __restrict__ wC,
        const float* __restrict__ wD, const float* __restrict__ l1w3,
        const float* __restrict__ wf2, const float* __restrict__ wfc1,
        const float* __restrict__ bfc1, const float* __restrict__ bfc2,
        unsigned short* __restrict__ l1g, double* __restrict__ partials1,
        float* __restrict__ w2s) {
    __shared__ __align__(16) float xs[S1 * 784];   // 25088 B; reused as bf16 out buffer
    __shared__ float wls[4], wlss[4];
    int t = threadIdx.x;

    // stage x tile: issue global loads first
    const float4* src = (const float4*)(x + (size_t)blockIdx.x * (S1 * 784));
    float4 rbuf[6];
    #pragma unroll
    for (int i = 0; i < 6; ++i) rbuf[i] = src[t + 256 * i];
    float4 rtail;
    if (t < 32) rtail = src[t + 1536];

    // self-prep fused weights for this thread's position (L2-resident inputs)
    bool active = t < 196;
    int pos = active ? t : 0;
    int pi = pos / 14, pj = pos - 14 * pi;
    int r0 = (2 * pi) * 28 + 2 * pj;
    float4 a0, a1, a2, a3;
    {
        float2 wt = *(const float2*)(l1w1 + r0);
        float2 wb = *(const float2*)(l1w1 + r0 + 28);
        a0 = make_float4(wt.x, wt.y, wb.x, wb.y);
        float mA0 = (pj != 0) ? 1.f : 0.f, mA1 = (pj != 13) ? 1.f : 0.f;
        float mB0 = (pi != 0) ? 1.f : 0.f, mB1 = (pi != 13) ? 1.f : 0.f;
        float eA[4] = {mA0, mA1, mA0, mA1};
        float eB[4] = {mB0, mB0, mB1, mB1};
        const int e1i[10] = {0,1,2,3,0,0,0,1,1,2};
        const int e2i[10] = {0,1,2,3,1,2,3,2,3,3};
        int wo = pi * 140 + 10 * pj;
        float wq[10];
        #pragma unroll
        for (int k = 0; k < 10; ++k) {
            float ca = eA[e1i[k]] * eA[e2i[k]];
            float cb = eB[e1i[k]] * eB[e2i[k]];
            wq[k] = wA[wo + k] * ca + wB[wo + k] * cb
                  + wC[wo + k] * ca * cb + wD[wo + k];
        }
        a1 = make_float4(wq[0], wq[1], wq[2], wq[3]);
        a2 = make_float4(wq[4], wq[5], wq[6], wq[7]);
        a3 = make_float4(wq[8], wq[9], l1w3[pos], 0.f);
    }

    float4* dst = (float4*)xs;
    #pragma unroll
    for (int i = 0; i < 6; ++i) dst[t + 256 * i] = rbuf[i];
    if (t < 32) dst[t + 1536] = rtail;
    __syncthreads();

    float accs[S1];
    float sum = 0.f, sumsq = 0.f;
    #pragma unroll
    for (int s = 0; s < S1; ++s) {
        const float* xb = xs + s * 784;
        float2 tp = *(const float2*)(xb + r0);
        float2 bo = *(const float2*)(xb + r0 + 28);
        float b00 = tp.x, b01 = tp.y, b10 = bo.x, b11 = bo.y;
        float acc = b00 * a0.x + b01 * a0.y + b10 * a0.z + b11 * a0.w;
        acc += b00 * b00 * a1.x + b01 * b01 * a1.y + b10 * b10 * a1.z + b11 * b11 * a1.w;
        acc += b00 * b01 * a2.x + b00 * b10 * a2.y + b00 * b11 * a2.z + b01 * b10 * a2.w;
        acc += b01 * b11 * a3.x + b10 * b11 * a3.y + a3.z;
        accs[s] = acc;
        if (active) { sum += acc; sumsq += acc * acc; }
    }

    // bf16 gathered-layout store via LDS transpose (xs reused)
    __syncthreads();
    unsigned short* ob = (unsigned short*)xs;
    if (active) {
        int g = ((pi >> 1) * 7 + (pj >> 1)) * 4 + (pi & 1) * 2 + (pj & 1);
        #pragma unroll
        for (int s = 0; s < S1; ++s) ob[s * 196 + g] = f2bf(accs[s]);
    }
    __syncthreads();
    const unsigned int* ob32 = (const unsigned int*)ob;
    unsigned int* gout = (unsigned int*)(l1g + (size_t)blockIdx.x * (S1 * 196));
    #pragma unroll
    for (int r2 = 0; r2 < 3; ++r2) gout[t + 256 * r2] = ob32[t + 256 * r2];
    if (t < 16) gout[t + 768] = ob32[t + 768];

    // per-block stats -> unique slot (no atomics, no zero-init needed)
    #pragma unroll
    for (int off = 32; off; off >>= 1) {
        sum += __shfl_down(sum, off);
        sumsq += __shfl_down(sumsq, off);
    }
    int lane = t & 63, wid = t >> 6;
    if (lane == 0) { wls[wid] = sum; wlss[wid] = sumsq; }
    __syncthreads();
    if (t == 0) {
        partials1[blockIdx.x * 2]     = (double)(wls[0] + wls[1] + wls[2] + wls[3]);
        partials1[blockIdx.x * 2 + 1] = (double)(wlss[0] + wlss[1] + wlss[2] + wlss[3]);
    }

    // blocks 0..9: build symmetric FC table w2s[50][50][10]
    if (blockIdx.x < 10) {
        int e = blockIdx.x * 256 + t;
        if (e < 2500) {
            int p = e / 50, q = e - 50 * p;
            float w[10];
            if (p < 49 && q < 49) {
                int lo = p < q ? p : q, hi = p < q ? q : p;
                float sc = (p == q) ? 1.f : 0.5f;
                #pragma unroll
                for (int o = 0; o < 10; ++o) w[o] = wf2[o * 2401 + lo * 49 + hi] * sc;
            } else if (p == 49 && q < 49) {
                #pragma unroll
                for (int o = 0; o < 10; ++o) w[o] = wfc1[o * 49 + q];
            } else if (p < 49) {   // q == 49
                #pragma unroll
                for (int o = 0; o < 10; ++o) w[o] = 0.f;
            } else {               // p == q == 49: biases
                #pragma unroll
                for (int o = 0; o < 10; ++o) w[o] = bfc1[o] + bfc2[o];
            }
            #pragma unroll
            for (int o = 0; o < 10; ++o) w2s[e * 10 + o] = w[o];
        }
    }
}

// ---------------- k2: layer 2 (reduce partials1, no LDS staging) ----------------
__global__ void __launch_bounds__(256) k2(
        const unsigned short* __restrict__ l1g,
        const float* __restrict__ l2w1, const float* __restrict__ l2w2,
        const float* __restrict__ l2w4,
        const float* __restrict__ gamma, const float* __restrict__ beta,
        const double* __restrict__ partials1, double* __restrict__ partials2,
        float* __restrict__ l2g) {
    __shared__ float wls[4], wlss[4];
    __shared__ double dred[8];
    __shared__ float bcast[2];
    int t = threadIdx.x;
    int lane = t & 63, wid = t >> 6;
    int sbase = blockIdx.x * S1;

    bool active = t < 196;
    int tt = active ? t : 0;
    int sub = tt / 49;
    int pos = tt - 49 * sub;

    // issue l1g loads early (latency hides under stats reduce)
    ushort4 u0 = *(const ushort4*)(l1g + ((size_t)(sbase + sub) * 49 + pos) * 4);
    ushort4 u1 = *(const ushort4*)(l1g + ((size_t)(sbase + 4 + sub) * 49 + pos) * 4);

    // reduce 2048 partials -> (a1, c1)
    {
        double s = 0.0, ss = 0.0;
        const double* p1 = partials1 + t * 16;
        #pragma unroll
        for (int k = 0; k < 8; ++k) { s += p1[k * 2]; ss += p1[k * 2 + 1]; }
        #pragma unroll
        for (int off = 32; off; off >>= 1) {
            s += __shfl_down(s, off);
            ss += __shfl_down(ss, off);
        }
        if (lane == 0) { dred[wid * 2] = s; dred[wid * 2 + 1] = ss; }
        __syncthreads();
        if (t == 0) {
            double S = dred[0] + dred[2] + dred[4] + dred[6];
            double SS = dred[1] + dred[3] + dred[5] + dred[7];
            double mean = S / (double)N1;
            double var = SS / (double)N1 - mean * mean;
            float a = (float)((double)gamma[0] / sqrt(var + 1e-5));
            bcast[0] = a;
            bcast[1] = beta[0] - (float)mean * a;
        }
    }

    // self-prep layer-2 per-position weights
    int pi = pos / 7, pj = pos - 7 * pi;
    int r0 = (2 * pi) * 14 + 2 * pj;
    float4 a0 = make_float4(l2w1[r0], l2w1[r0 + 1], l2w1[r0 + 14], l2w1[r0 + 15]);
    int wo = pi * 70 + 10 * pj;
    float4 q1 = make_float4(l2w2[wo],     l2w2[wo + 1], l2w2[wo + 2], l2w2[wo + 3]);
    float4 q2 = make_float4(l2w2[wo + 4], l2w2[wo + 5], l2w2[wo + 6], l2w2[wo + 7]);
    float4 q3 = make_float4(l2w2[wo + 8], l2w2[wo + 9], l2w4[pos], 0.f);
    __syncthreads();
    float a1 = bcast[0], c1 = bcast[1];

    float sum = 0.f, sumsq = 0.f;
    #pragma unroll
    for (int s2 = 0; s2 < 2; ++s2) {
        ushort4 u = s2 ? u1 : u0;
        int smp = sbase + s2 * 4 + sub;
        float h00 = fmaf(a1, bf2f(u.x), c1), h01 = fmaf(a1, bf2f(u.y), c1);
        float h10 = fmaf(a1, bf2f(u.z), c1), h11 = fmaf(a1, bf2f(u.w), c1);
        float acc = h00 * a0.x + h01 * a0.y + h10 * a0.z + h11 * a0.w;
        acc += h00 * h00 * q1.x + h01 * h01 * q1.y + h10 * h10 * q1.z + h11 * h11 * q1.w;
        acc += h00 * h01 * q2.x + h00 * h10 * q2.y + h00 * h11 * q2.z + h01 * h10 * q2.w;
        acc += h01 * h11 * q3.x + h10 * h11 * q3.y + q3.z;
        if (active) {
            l2g[(size_t)smp * 52 + pos] = acc;
            sum += acc;
            sumsq += acc * acc;
        }
    }

    #pragma unroll
    for (int off = 32; off; off >>= 1) {
        sum += __shfl_down(sum, off);
        sumsq += __shfl_down(sumsq, off);
    }
    if (lane == 0) { wls[wid] = sum; wlss[wid] = sumsq; }
    __syncthreads();
    if (t == 0) {
        partials2[blockIdx.x * 2]     = (double)(wls[0] + wls[1] + wls[2] + wls[3]);
        partials2[blockIdx.x * 2 + 1] = (double)(wlss[0] + wlss[1] + wlss[2] + wlss[3]);
    }
}

// ---------------- k3: FC via symmetric table, uniform code, 16 row-partitions ----------------
__global__ void __launch_bounds__(1024) k3(
        const float* __restrict__ l2g, const float* __restrict__ w2s,
        const float* __restrict__ gamma, const float* __restrict__ beta,
        const double* __restrict__ partials2, float* __restrict__ out) {
    __shared__ float part[16][64][10];   // 40960 B
    __shared__ double dred[32];
    __shared__ float bcast[2];
    int t = threadIdx.x, lane = t & 63, wid = t >> 6;
    int s = blockIdx.x * 64 + lane;

    // issue v loads early
    float v[52];
    const float4* vsrc = (const float4*)(l2g + (size_t)s * 52);
    #pragma unroll
    for (int k = 0; k < 13; ++k) *(float4*)(v + 4 * k) = vsrc[k];

    // reduce 2048 partials -> (a2, c2)
    {
        const double* p2 = partials2 + t * 4;
        double sd = p2[0] + p2[2], ssd = p2[1] + p2[3];
        #pragma unroll
        for (int off = 32; off; off >>= 1) {
            sd += __shfl_down(sd, off);
            ssd += __shfl_down(ssd, off);
        }
        if (lane == 0) { dred[wid * 2] = sd; dred[wid * 2 + 1] = ssd; }
        __syncthreads();
        if (t == 0) {
            double S = 0.0, SS = 0.0;
            #pragma unroll
            for (int w = 0; w < 16; ++w) { S += dred[w * 2]; SS += dred[w * 2 + 1]; }
            double mean = S / (double)N2;
            double var = SS / (double)N2 - mean * mean;
            float a = (float)((double)gamma[0] / sqrt(var + 1e-5));
            bcast[0] = a;
            bcast[1] = beta[0] - (float)mean * a;
        }
        __syncthreads();
    }
    float a2 = bcast[0], c2 = bcast[1];
    #pragma unroll
    for (int k = 0; k < 49; ++k) v[k] = fmaf(a2, v[k], c2);
    v[49] = 1.f;

    float acc[10];
    #pragma unroll
    for (int o = 0; o < 10; ++o) acc[o] = 0.f;

    int W = __builtin_amdgcn_readfirstlane(wid);
    for (int r = W; r < 50; r += 16) {
        float vp = (r < 49) ? fmaf(a2, l2g[(size_t)s * 52 + r], c2) : 1.f;
        const float* wr = w2s + r * 500;
        #pragma unroll
        for (int q = 0; q < 50; ++q) {
            float c = vp * v[q];
            #pragma unroll
            for (int o = 0; o < 10; ++o) acc[o] = fmaf(c, wr[q * 10 + o], acc[o]);
        }
    }

    #pragma unroll
    for (int o = 0; o < 10; ++o) part[wid][lane][o] = acc[o];
    __syncthreads();

    if (t < 640) {
        int sl = t / 10, o = t - 10 * sl;
        float r2 = 0.f;
        #pragma unroll
        for (int w = 0; w < 16; ++w) r2 += part[w][sl][o];
        out[(size_t)(blockIdx.x * 64 + sl) * 10 + o] = r2;   // biases in table row 49
    }
}

extern "C" void kernel_launch(void* const* d_in, const int* in_sizes, int n_in,
                              void* d_out, int out_size, void* d_ws, size_t ws_size,
                              hipStream_t stream) {
    const float* x       = (const float*)d_in[0];
    const float* l1_w1   = (const float*)d_in[1];
    const float* l1_w2_1 = (const float*)d_in[2];
    const float* l1_w2_2 = (const float*)d_in[3];
    const float* l1_w2_3 = (const float*)d_in[4];
    const float* l1_w2_4 = (const float*)d_in[5];
    const float* l1_w3   = (const float*)d_in[6];
    const float* l2_w1   = (const float*)d_in[7];
    const float* l2_w2   = (const float*)d_in[8];
    const float* l2_w4   = (const float*)d_in[9];
    const float* w_fc1   = (const float*)d_in[10];
    const float* b_fc1   = (const float*)d_in[11];
    const float* w_fc2   = (const float*)d_in[12];
    const float* b_fc2   = (const float*)d_in[13];
    const float* bn_gamma = (const float*)d_in[14];
    const float* bn_beta  = (const float*)d_in[15];

    char* ws = (char*)d_ws;
    double* partials1 = (double*)(ws + WS_P1_OFF);
    double* partials2 = (double*)(ws + WS_P2_OFF);
    float* w2s = (float*)(ws + WS_W2S_OFF);
    unsigned short* l1g = (unsigned short*)(ws + WS_L1G_OFF);
    float* l2g = (float*)(ws + WS_L2G_OFF);
    float* out = (float*)d_out;

    k1<<<BATCH / S1, 256, 0, stream>>>(x, l1_w1, l1_w2_1, l1_w2_2, l1_w2_3, l1_w2_4,
                                       l1_w3, w_fc2, w_fc1, b_fc1, b_fc2,
                                       l1g, partials1, w2s);
    k2<<<BATCH / S1, 256, 0, stream>>>(l1g, l2_w1, l2_w2, l2_w4, bn_gamma, bn_beta,
                                       partials1, partials2, l2g);
    k3<<<BATCH / 64, 1024, 0, stream>>>(l2g, w2s, bn_gamma, bn_beta, partials2, out);
}